// Round 1
// baseline (178.386 us; speedup 1.0000x reference)
//
#include <hip/hip_runtime.h>

// x: (B, C, D, H, W) float32; out: (B, D, H, W) float32 = log(det(I+grad u))^2.
constexpr int B = 2, C = 3, D = 128, H = 192, W = 192;
constexpr int sH = W;          // stride of h (elements)
constexpr int sD = H * W;      // stride of d
constexpr int sC = D * H * W;  // stride of c
constexpr int sB = C * sC;     // stride of b

constexpr int TH = 16;           // tile h-rows
constexpr int TW = 16;           // tile f4-groups (64 floats wide)
constexpr int DC = 8;            // d-planes marched per block (was 4)
constexpr int HX = H / TH;       // 12 h-tiles
constexpr int WX = (W / 4) / TW; // 3 w-tiles
constexpr int NDC = D / DC;      // 16 d-chunks
constexpr int NB = B * NDC * HX * WX;  // 1152 blocks (4.5 blocks/CU)
constexpr int ROWS = TH + 2;     // 18 staged rows (h-halo)
constexpr int RSTR = TW + 1;     // row stride in f4 (+1 pad vs bank aliasing)
constexpr int CH_STR = ROWS * RSTR;    // 306 f4 per channel
constexpr int BUFSZ = C * CH_STR;      // 918 f4 per buffer (14.7 KB)

// Depth-1 software pipeline over d: iteration dd computes plane d entirely
// from already-resident registers (cm=d-1, c0=d, cp=d+1) + LDS[dd&1] (plane d
// staged last iteration), while issuing the loads for plane d+2 / halo(d+2) /
// w-edges(d+1). Every global load gets a full iteration (compute + stage +
// barrier) of cover before first use. DC=8 amortizes the prologue: d-halo
// over-read drops 1.5x -> 1.25x.
__global__ __launch_bounds__(256, 4) void jac_logdet_sq(
    const float* __restrict__ x, float* __restrict__ out) {
    __shared__ float4 lds[2][BUFSZ];

    const int tid = threadIdx.x;
    const int tx = tid & 15;
    const int ty = tid >> 4;

    int bb = blockIdx.x;
    const int wx = bb % WX; bb /= WX;
    const int hx = bb % HX; bb /= HX;
    const int dch = bb % NDC;
    const int b = bb / NDC;

    const int d0 = dch * DC;
    const int h0 = hx * TH;
    const int h = h0 + ty;
    const int w0 = (wx * TW + tx) * 4;

    const float* pb = x + b * sB;
    const int cidx = h * sH + w0;     // (h,w) offset within one (c,d) plane

    // halo staging role (tid < 96): channel hc, top/bottom row hr, col htx
    const int hc = tid / 32;
    const int hr = (tid >> 4) & 1;
    const int htx = tid & 15;
    const int hh = hr ? ((h0 + TH < H) ? h0 + TH : H - 1)
                      : ((h0 > 0) ? h0 - 1 : 0);
    const int hidx = hh * sH + (wx * TW + htx) * 4;
    const int hlds = hc * CH_STR + (hr ? (TH + 1) : 0) * RSTR + htx;

    const float chc = (h > 0 && h < H - 1) ? 0.5f : 1.0f;

    float4 cm[3], c0[3], cp[3], cn[3];
    float4 hv0, hvp, hvn;
    float lg[3], rg[3], lgn[3], rgn[3];

    // ---- prologue: window {d0-1, d0, d0+1}; stage d0; edges(d0); halo(d0+1)
    const int dm = (d0 > 0) ? d0 - 1 : 0;   // d0+1 <= D-1 always (DC >= 2)
#pragma unroll
    for (int c = 0; c < 3; ++c) {
        c0[c] = *(const float4*)(pb + c * sC + d0 * sD + cidx);
        cm[c] = *(const float4*)(pb + c * sC + dm * sD + cidx);
        cp[c] = *(const float4*)(pb + c * sC + (d0 + 1) * sD + cidx);
    }
    if (tid < 96) {
        hv0 = *(const float4*)(pb + hc * sC + d0 * sD + hidx);
        hvp = *(const float4*)(pb + hc * sC + (d0 + 1) * sD + hidx);
    }
    if (tx == 0 && w0 > 0) {
#pragma unroll
        for (int c = 0; c < 3; ++c) lg[c] = pb[c * sC + d0 * sD + cidx - 1];
    }
    if (tx == 15 && w0 + 4 < W) {
#pragma unroll
        for (int c = 0; c < 3; ++c) rg[c] = pb[c * sC + d0 * sD + cidx + 4];
    }
#pragma unroll
    for (int c = 0; c < 3; ++c)
        lds[0][c * CH_STR + (ty + 1) * RSTR + tx] = c0[c];
    if (tid < 96) lds[0][hlds] = hv0;
    __syncthreads();

    int obase = ((b * D + d0) * H + h) * W + w0;

#pragma unroll
    for (int dd = 0; dd < DC; ++dd) {
        const int d = d0 + dd;
        const float cdc = (d > 0 && d < D - 1) ? 0.5f : 1.0f;
        const float4* bufc = lds[dd & 1];        // plane d (staged last iter)

        // ---- d-gradient first (frees cm before cn lands) ----
        float gd[3][4], gh[3][4], gw[3][4];
#pragma unroll
        for (int c = 0; c < 3; ++c) {
            gd[c][0] = (cp[c].x - cm[c].x) * cdc;
            gd[c][1] = (cp[c].y - cm[c].y) * cdc;
            gd[c][2] = (cp[c].z - cm[c].z) * cdc;
            gd[c][3] = (cp[c].w - cm[c].w) * cdc;
        }

        // ---- prefetch for iter dd+1: plane d+2 regs, halo(d+2), edges(d+1)
        if (dd < DC - 1) {
            const int dpp = (d + 2 < D) ? d + 2 : D - 1;
#pragma unroll
            for (int c = 0; c < 3; ++c)
                cn[c] = *(const float4*)(pb + c * sC + dpp * sD + cidx);
            if (dd < DC - 2 && tid < 96)
                hvn = *(const float4*)(pb + hc * sC + dpp * sD + hidx);
            if (tx == 0 && w0 > 0) {
#pragma unroll
                for (int c = 0; c < 3; ++c)
                    lgn[c] = pb[c * sC + (d + 1) * sD + cidx - 1];
            }
            if (tx == 15 && w0 + 4 < W) {
#pragma unroll
                for (int c = 0; c < 3; ++c)
                    rgn[c] = pb[c * sC + (d + 1) * sD + cidx + 4];
            }
        }

        // ---- h/w gradients from LDS (plane d) + c0 regs ----
#pragma unroll
        for (int c = 0; c < 3; ++c) {
            const float4 hp = bufc[c * CH_STR + (ty + 2) * RSTR + tx];
            const float4 hm = bufc[c * CH_STR + (ty    ) * RSTR + tx];
            gh[c][0] = (hp.x - hm.x) * chc;
            gh[c][1] = (hp.y - hm.y) * chc;
            gh[c][2] = (hp.z - hm.z) * chc;
            gh[c][3] = (hp.w - hm.w) * chc;

            const float lft = (tx == 0) ? lg[c]
                : bufc[c * CH_STR + (ty + 1) * RSTR + tx - 1].w;
            const float rgt = (tx == 15) ? rg[c]
                : bufc[c * CH_STR + (ty + 1) * RSTR + tx + 1].x;
            gw[c][0] = (w0 == 0)     ? (c0[c].y - c0[c].x)
                                     : 0.5f * (c0[c].y - lft);
            gw[c][1] = 0.5f * (c0[c].z - c0[c].x);
            gw[c][2] = 0.5f * (c0[c].w - c0[c].y);
            gw[c][3] = (w0 + 4 == W) ? (c0[c].w - c0[c].z)
                                     : 0.5f * (rgt - c0[c].z);
        }

        float r[4];
#pragma unroll
        for (int e = 0; e < 4; ++e) {
            const float a00 = gd[0][e] + 1.0f, a01 = gd[1][e], a02 = gd[2][e];
            const float a10 = gh[0][e], a11 = gh[1][e] + 1.0f, a12 = gh[2][e];
            const float a20 = gw[0][e], a21 = gw[1][e], a22 = gw[2][e] + 1.0f;
            const float det = a00 * (a11 * a22 - a12 * a21)
                            - a01 * (a10 * a22 - a12 * a20)
                            + a02 * (a10 * a21 - a11 * a20);
            const float l = __logf(det);  // det>0; HW log, validated R3
            r[e] = l * l;
        }
        *(float4*)(out + obase) = make_float4(r[0], r[1], r[2], r[3]);
        obase += sD;

        // ---- stage plane d+1 (cp, hvp: both long-arrived) into other buffer
        if (dd < DC - 1) {
#pragma unroll
            for (int c = 0; c < 3; ++c)
                lds[(dd + 1) & 1][c * CH_STR + (ty + 1) * RSTR + tx] = cp[c];
            if (tid < 96) lds[(dd + 1) & 1][hlds] = hvp;
            __syncthreads();

            // rotate window (full unroll -> renamed, no v_mov chains)
#pragma unroll
            for (int c = 0; c < 3; ++c) {
                cm[c] = c0[c]; c0[c] = cp[c]; cp[c] = cn[c];
                lg[c] = lgn[c]; rg[c] = rgn[c];
            }
            hvp = hvn;
        }
    }
}

extern "C" void kernel_launch(void* const* d_in, const int* in_sizes, int n_in,
                              void* d_out, int out_size, void* d_ws, size_t ws_size,
                              hipStream_t stream) {
    const float* x = (const float*)d_in[0];
    float* out = (float*)d_out;
    jac_logdet_sq<<<dim3(NB), dim3(256), 0, stream>>>(x, out);
}

// Round 2
// 176.224 us; speedup vs baseline: 1.0123x; 1.0123x over previous
//
#include <hip/hip_runtime.h>

// x: (B, C, D, H, W) float32; out: (B, D, H, W) float32 = log(det(I+grad u))^2.
constexpr int B = 2, C = 3, D = 128, H = 192, W = 192;
constexpr int sH = W;          // stride of h (elements)
constexpr int sD = H * W;      // stride of d
constexpr int sC = D * H * W;  // stride of c
constexpr int sB = C * sC;     // stride of b

constexpr int THREADS = 384;     // 6 waves
constexpr int TH = 8;            // tile h-rows
constexpr int TWQ = W / 4;       // 48 f4-groups = FULL W row (no w-seams!)
constexpr int DC = 8;            // d-planes marched per block
constexpr int HX = H / TH;       // 24 h-tiles
constexpr int NDC = D / DC;      // 16 d-chunks
constexpr int NB = B * NDC * HX; // 768 blocks = exactly 3/CU, zero tail
constexpr int ROWS = TH + 2;     // 10 staged rows (h-halo)
constexpr int RSTR = TWQ + 1;    // 49 f4 row stride (+1 pad vs bank aliasing)
constexpr int CH_STR = ROWS * RSTR;    // 490 f4 per channel
constexpr int BUFSZ = C * CH_STR;      // 1470 f4 per buffer (23.5 KB)

// Full-W tiles kill the w-seam scalar loads (96 cold 64B lines per plane per
// block in the old 64-float tiles = +44% wasted HBM/L2 line traffic — the
// shared limiter that made R0 and R1 identical). Every w-neighbor now comes
// from LDS; true image edges use one-sided differences. Depth-1 d-pipeline
// retained: iter dd computes plane d from regs (cm,c0,cp) + LDS[dd&1] while
// loading plane d+2 and halo(d+2).
__global__ __launch_bounds__(THREADS, 4) void jac_logdet_sq(
    const float* __restrict__ x, float* __restrict__ out) {
    __shared__ float4 lds[2][BUFSZ];   // 47 KB -> 3 blocks/CU

    const int tid = threadIdx.x;
    const int tx = tid % TWQ;          // f4-group 0..47 (w)
    const int ty = tid / TWQ;          // row 0..7 (h)

    int bb = blockIdx.x;
    const int hx = bb % HX; bb /= HX;
    const int dch = bb % NDC;
    const int b = bb / NDC;

    const int d0 = dch * DC;
    const int h0 = hx * TH;
    const int h = h0 + ty;
    const int w0 = tx * 4;

    const float* pb = x + b * sB;
    const int cidx = h * sH + w0;      // (h,w) offset within one (c,d) plane

    // halo staging role (tid < 288): channel hc, top/bottom row hrr, col htx
    const int hc = tid / 96;           // 0..2 (tid<288), 4 for tid>=384? no: <=3
    const int hrem = tid % 96;
    const int hrr = hrem / TWQ;        // 0=top halo, 1=bottom halo
    const int htx = hrem % TWQ;
    const int hh = hrr ? ((h0 + TH < H) ? h0 + TH : H - 1)
                       : ((h0 > 0) ? h0 - 1 : 0);
    const int hidx = hh * sH + htx * 4;
    const int hlds = hc * CH_STR + (hrr ? (TH + 1) : 0) * RSTR + htx;
    const bool halo = (tid < 288);

    const float chc = (h > 0 && h < H - 1) ? 0.5f : 1.0f;

    float4 cm[3], c0[3], cp[3], cn[3];
    float4 hv0, hvp, hvn;

    // ---- prologue: window {d0-1, d0, d0+1}; stage d0 + halo(d0) ----
    const int dm = (d0 > 0) ? d0 - 1 : 0;   // d0+1 <= D-1 always (DC >= 2)
#pragma unroll
    for (int c = 0; c < 3; ++c) {
        c0[c] = *(const float4*)(pb + c * sC + d0 * sD + cidx);
        cm[c] = *(const float4*)(pb + c * sC + dm * sD + cidx);
        cp[c] = *(const float4*)(pb + c * sC + (d0 + 1) * sD + cidx);
    }
    if (halo) {
        hv0 = *(const float4*)(pb + hc * sC + d0 * sD + hidx);
        hvp = *(const float4*)(pb + hc * sC + (d0 + 1) * sD + hidx);
    }
#pragma unroll
    for (int c = 0; c < 3; ++c)
        lds[0][c * CH_STR + (ty + 1) * RSTR + tx] = c0[c];
    if (halo) lds[0][hlds] = hv0;
    __syncthreads();

    int obase = ((b * D + d0) * H + h) * W + w0;

#pragma unroll
    for (int dd = 0; dd < DC; ++dd) {
        const int d = d0 + dd;
        const float cdc = (d > 0 && d < D - 1) ? 0.5f : 1.0f;
        const float4* bufc = lds[dd & 1];        // plane d (staged last iter)

        // ---- d-gradient first (frees cm before cn lands) ----
        float gd[3][4], gh[3][4], gw[3][4];
#pragma unroll
        for (int c = 0; c < 3; ++c) {
            gd[c][0] = (cp[c].x - cm[c].x) * cdc;
            gd[c][1] = (cp[c].y - cm[c].y) * cdc;
            gd[c][2] = (cp[c].z - cm[c].z) * cdc;
            gd[c][3] = (cp[c].w - cm[c].w) * cdc;
        }

        // ---- prefetch for iter dd+1: plane d+2 regs, halo(d+2) ----
        if (dd < DC - 1) {
            const int dpp = (d + 2 < D) ? d + 2 : D - 1;
#pragma unroll
            for (int c = 0; c < 3; ++c)
                cn[c] = *(const float4*)(pb + c * sC + dpp * sD + cidx);
            if (dd < DC - 2 && halo)
                hvn = *(const float4*)(pb + hc * sC + dpp * sD + hidx);
        }

        // ---- h/w gradients from LDS (plane d) + c0 regs ----
#pragma unroll
        for (int c = 0; c < 3; ++c) {
            const float4 hp = bufc[c * CH_STR + (ty + 2) * RSTR + tx];
            const float4 hm = bufc[c * CH_STR + (ty    ) * RSTR + tx];
            gh[c][0] = (hp.x - hm.x) * chc;
            gh[c][1] = (hp.y - hm.y) * chc;
            gh[c][2] = (hp.z - hm.z) * chc;
            gh[c][3] = (hp.w - hm.w) * chc;

            // w-neighbors entirely from LDS; clamp index, value unused at edge
            const int txl = (tx > 0) ? tx - 1 : tx;
            const int txr = (tx < TWQ - 1) ? tx + 1 : tx;
            const float lft = bufc[c * CH_STR + (ty + 1) * RSTR + txl].w;
            const float rgt = bufc[c * CH_STR + (ty + 1) * RSTR + txr].x;
            gw[c][0] = (tx == 0)       ? (c0[c].y - c0[c].x)
                                       : 0.5f * (c0[c].y - lft);
            gw[c][1] = 0.5f * (c0[c].z - c0[c].x);
            gw[c][2] = 0.5f * (c0[c].w - c0[c].y);
            gw[c][3] = (tx == TWQ - 1) ? (c0[c].w - c0[c].z)
                                       : 0.5f * (rgt - c0[c].z);
        }

        float r[4];
#pragma unroll
        for (int e = 0; e < 4; ++e) {
            const float a00 = gd[0][e] + 1.0f, a01 = gd[1][e], a02 = gd[2][e];
            const float a10 = gh[0][e], a11 = gh[1][e] + 1.0f, a12 = gh[2][e];
            const float a20 = gw[0][e], a21 = gw[1][e], a22 = gw[2][e] + 1.0f;
            const float det = a00 * (a11 * a22 - a12 * a21)
                            - a01 * (a10 * a22 - a12 * a20)
                            + a02 * (a10 * a21 - a11 * a20);
            const float l = __logf(det);  // det>0; HW log, validated R3
            r[e] = l * l;
        }
        *(float4*)(out + obase) = make_float4(r[0], r[1], r[2], r[3]);
        obase += sD;

        // ---- stage plane d+1 (cp, hvp: both long-arrived) ----
        if (dd < DC - 1) {
#pragma unroll
            for (int c = 0; c < 3; ++c)
                lds[(dd + 1) & 1][c * CH_STR + (ty + 1) * RSTR + tx] = cp[c];
            if (halo) lds[(dd + 1) & 1][hlds] = hvp;
            __syncthreads();

            // rotate window (unrolled -> register-renamed)
#pragma unroll
            for (int c = 0; c < 3; ++c) {
                cm[c] = c0[c]; c0[c] = cp[c]; cp[c] = cn[c];
            }
            hvp = hvn;
        }
    }
}

extern "C" void kernel_launch(void* const* d_in, const int* in_sizes, int n_in,
                              void* d_out, int out_size, void* d_ws, size_t ws_size,
                              hipStream_t stream) {
    const float* x = (const float*)d_in[0];
    float* out = (float*)d_out;
    jac_logdet_sq<<<dim3(NB), dim3(THREADS), 0, stream>>>(x, out);
}